// Round 11
// baseline (224.452 us; speedup 1.0000x reference)
//
#include <hip/hip_runtime.h>
#include <hip/hip_bf16.h>

#define HW 4096
#define CCH 64

typedef __attribute__((ext_vector_type(8))) short short8;
typedef __attribute__((ext_vector_type(4))) float f32x4;
typedef unsigned short ushort_t;
typedef unsigned long long u64;

#define SCALE_Q 0.18033688f  // (1/sqrt(64)) * log2(e)

__device__ __forceinline__ unsigned short f2b(float f) {
  unsigned u = __float_as_uint(f);
  return (unsigned short)((u + 0x7fff + ((u >> 16) & 1)) >> 16);  // RNE
}
__device__ __forceinline__ float b2f(ushort_t u) {
  return __uint_as_float(((unsigned)u) << 16);
}
__device__ __forceinline__ unsigned cvtpk(float lo, float hi) {
  unsigned r;
  asm volatile("v_cvt_pk_bf16_f32 %0, %1, %2" : "=v"(r) : "v"(lo), "v"(hi));
  return r;
}
__device__ __forceinline__ void gload16(const void* g, void* l) {
  __builtin_amdgcn_global_load_lds(
      (const __attribute__((address_space(1))) unsigned int*)g,
      (__attribute__((address_space(3))) unsigned int*)l, 16, 0, 0);
}

// ------------- depthwise convs (3x3 pad1 + 5x5 pad2, reflect) + GN partial slots -------------
__global__ void __launch_bounds__(256) k_dwconv(
    const float* __restrict__ in, const float* __restrict__ w1, const float* __restrict__ b1,
    const float* __restrict__ w2, const float* __restrict__ b2,
    ushort_t* __restrict__ x, ushort_t* __restrict__ y, float* __restrict__ sums) {
  __shared__ float sm[20 * 68];
  __shared__ float red[4][4];
  const int bc = blockIdx.x >> 2;
  const int strip = blockIdx.x & 3;
  const int r0 = strip * 16;
  const int c = bc & 63;
  const float* p = in + bc * HW;
  const int tid = threadIdx.x;
  for (int idx = tid; idx < 20 * 68; idx += 256) {
    int r = r0 + idx / 68 - 2, cc = idx % 68 - 2;
    r = r < 0 ? -r : (r > 63 ? 126 - r : r);
    cc = cc < 0 ? -cc : (cc > 63 ? 126 - cc : cc);
    sm[idx] = p[r * 64 + cc];
  }
  float w1r[9], w2r[25];
  for (int i = 0; i < 9; i++) w1r[i] = w1[c * 9 + i];
  for (int i = 0; i < 25; i++) w2r[i] = w2[c * 25 + i];
  const float bb1 = b1[c], bb2 = b2[c];
  __syncthreads();

  const int i = tid >> 4;
  const int j0 = (tid & 15) * 4;
  float rv[5][8];
  for (int u = 0; u < 5; u++) {
    *(f32x4*)&rv[u][0] = *(const f32x4*)&sm[(i + u) * 68 + j0];
    *(f32x4*)&rv[u][4] = *(const f32x4*)&sm[(i + u) * 68 + j0 + 4];
  }
  float a1[4], a2[4];
  for (int px = 0; px < 4; px++) {
    float s2 = bb2;
    for (int u = 0; u < 5; u++)
      for (int v = 0; v < 5; v++) s2 += w2r[u * 5 + v] * rv[u][px + v];
    float s1 = bb1;
    for (int u = 0; u < 3; u++)
      for (int v = 0; v < 3; v++) s1 += w1r[u * 3 + v] * rv[u + 1][px + 1 + v];
    a1[px] = s1 > 0.f ? s1 : 0.01f * s1;
    a2[px] = s2 > 0.f ? s2 : 0.01f * s2;
  }
  ushort_t t1[4], t2[4];
  for (int px = 0; px < 4; px++) { t1[px] = f2b(a1[px]); t2[px] = f2b(a2[px]); }
  const int off = bc * HW + (r0 + i) * 64 + j0;
  *(u64*)(x + off) = *(const u64*)t1;
  *(u64*)(y + off) = *(const u64*)t2;

  float s1 = 0, q1 = 0, s2 = 0, q2 = 0;
  for (int px = 0; px < 4; px++) {
    s1 += a1[px]; q1 += a1[px] * a1[px];
    s2 += a2[px]; q2 += a2[px] * a2[px];
  }
  for (int o = 1; o < 64; o <<= 1) {
    s1 += __shfl_xor(s1, o); q1 += __shfl_xor(q1, o);
    s2 += __shfl_xor(s2, o); q2 += __shfl_xor(q2, o);
  }
  if ((tid & 63) == 0) {
    red[tid >> 6][0] = s1; red[tid >> 6][1] = q1;
    red[tid >> 6][2] = s2; red[tid >> 6][3] = q2;
  }
  __syncthreads();
  if (tid == 0) {
    float r4[4];
    for (int k = 0; k < 4; k++)
      r4[k] = red[0][k] + red[1][k] + red[2][k] + red[3][k];
    sums[bc * 8 + strip * 2 + 0] = r4[0];
    sums[bc * 8 + strip * 2 + 1] = r4[1];
    sums[2048 + bc * 8 + strip * 2 + 0] = r4[2];
    sums[2048 + bc * 8 + strip * 2 + 1] = r4[3];
  }
}

// GN scale/shift for channel ch of branch (b,br): 2 vec loads + 2 shfl.
__device__ __forceinline__ void gn_coeffs(
    const float* __restrict__ sums, int b, int br, int ch,
    const float* __restrict__ gw, const float* __restrict__ gb,
    float& sc_out, float& sh_out) {
  const float* pp = sums + br * 2048 + (b * 64 + ch) * 8;
  const f32x4 pa = *(const f32x4*)pp;
  const f32x4 pb = *(const f32x4*)(pp + 4);
  float s = pa[0] + pa[2] + pb[0] + pb[2];
  float ss = pa[1] + pa[3] + pb[1] + pb[3];
  s += __shfl_xor(s, 1); ss += __shfl_xor(ss, 1);
  s += __shfl_xor(s, 2); ss += __shfl_xor(ss, 2);
  const float mu = s * (1.f / 16384.f);
  const float var = ss * (1.f / 16384.f) - mu * mu;
  const float rsig = rsqrtf(var + 1e-5f);
  const float a = rsig * gw[ch];
  sc_out = a;
  sh_out = gb[ch] - mu * a;
}

// -------- qkv projection (GN inline): Qt(pre-scaled),Kt [h][pix][64], V [h][64][pix] --------
__global__ void __launch_bounds__(256) k_qkv(
    const ushort_t* __restrict__ xbf, const ushort_t* __restrict__ ybf,
    const float* __restrict__ sums,
    const float* __restrict__ gwA, const float* __restrict__ gbA,
    const float* __restrict__ gwB, const float* __restrict__ gbB,
    const float* __restrict__ wA, const float* __restrict__ wB,
    ushort_t* __restrict__ Qt, ushort_t* __restrict__ Kt, ushort_t* __restrict__ Vv) {
  __shared__ float scs[64], shs[64];
  const int id = blockIdx.x * 256 + threadIdx.x;
  const int pg = id & 1023;
  const int chunk = (id >> 10) % 24;
  const int h = id / (1024 * 24);
  const int b = h >> 1, br = h & 1;
  if (threadIdx.x < 64) {
    float a, sh;
    gn_coeffs(sums, b, br, threadIdx.x, br ? gwB : gwA, br ? gbB : gbA, a, sh);
    scs[threadIdx.x] = a;
    shs[threadIdx.x] = sh;
  }
  __syncthreads();
  const ushort_t* X = (br ? ybf : xbf) + b * (CCH * HW);
  const float* W = br ? wB : wA;
  const int pix0 = pg * 4;
  const int r0 = chunk * 8;
  float acc[8][4];
  for (int r = 0; r < 8; r++) for (int p = 0; p < 4; p++) acc[r][p] = 0.f;
  for (int cc = 0; cc < 64; cc++) {
    const float sc = scs[cc], sh = shs[cc];
    const u64 raw = *(const u64*)(X + cc * HW + pix0);
    f32x4 xv;
    for (int p = 0; p < 4; p++)
      xv[p] = b2f((ushort_t)(raw >> (16 * p))) * sc + sh;
    for (int r = 0; r < 8; r++) {
      float wv = W[(r0 + r) * 64 + cc];
      for (int p = 0; p < 4; p++) acc[r][p] += wv * xv[p];
    }
  }
  if (chunk < 16) {
    ushort_t* dst = chunk < 8 ? Qt : Kt;
    const float qs = chunk < 8 ? SCALE_Q : 1.0f;
    const int d0 = (chunk & 7) * 8;
    for (int p = 0; p < 4; p++) {
      short8 v;
      for (int r = 0; r < 8; r++) v[r] = (short)f2b(acc[r][p] * qs);
      *(short8*)(dst + ((h * HW + pix0 + p) << 6) + d0) = v;
    }
  } else {
    const int d0 = (chunk - 16) * 8;
    for (int r = 0; r < 8; r++) {
      ushort_t tmp[4];
      for (int p = 0; p < 4; p++) tmp[p] = f2b(acc[r][p]);
      *(u64*)(Vv + (h * CCH + d0 + r) * HW + pix0) = *(const u64*)tmp;
    }
  }
}

// --------- flash cross-attention: 32q/wave, in-block split-K x2, 1 block/CU ---------
// 256 blocks x 512 thr (8 waves). wave w: slice s=w>>2 (2048 keys), t=w&3 (32 queries).
// K/V frags read ONCE per iter, shared by both 16q groups. Addr math hoisted, unroll-2.
#define STAGE(B, ITN) do {                                              \
    gload16(gK0 + ((ITN) << 12), lds + (B)*32768 + (tid << 4));         \
    gload16(gK1 + ((ITN) << 12), lds + (B)*32768 + 16384 + (tid << 4)); \
    gload16(gV0 + (ITN)*64,      lds + (B)*32768 + 8192  + (tid << 4)); \
    gload16(gV1 + (ITN)*64,      lds + (B)*32768 + 24576 + (tid << 4)); \
  } while (0)

#define GROUP(QFA, QFB, MR, O, ACCL, GOFF) {                                   \
    f32x4 sa[4];                                                               \
    _Pragma("unroll") for (int c = 0; c < 4; c++) {                            \
      f32x4 zz = {0.f, 0.f, 0.f, 0.f};                                         \
      zz = __builtin_amdgcn_mfma_f32_16x16x32_bf16(ka[c][0], QFA, zz, 0,0,0);  \
      sa[c] = __builtin_amdgcn_mfma_f32_16x16x32_bf16(ka[c][1], QFB, zz, 0,0,0);\
    }                                                                          \
    float mloc = sa[0][0];                                                     \
    _Pragma("unroll") for (int c = 0; c < 4; c++)                              \
      _Pragma("unroll") for (int i = 0; i < 4; i++)                            \
        mloc = fmaxf(mloc, sa[c][i]);                                          \
    mloc = fmaxf(mloc, __shfl_xor(mloc, 16));                                  \
    mloc = fmaxf(mloc, __shfl_xor(mloc, 32));                                  \
    if (!__all(mloc <= MR + 8.f)) {                                            \
      const float mnew = fmaxf(MR, mloc);                                      \
      const float alpha = exp2f(MR - mnew);                                    \
      _Pragma("unroll") for (int cd = 0; cd < 4; cd++)                         \
        _Pragma("unroll") for (int i = 0; i < 4; i++) O[cd][i] *= alpha;       \
      _Pragma("unroll") for (int i = 0; i < 4; i++) ACCL[i] *= alpha;          \
      MR = mnew;                                                               \
    }                                                                          \
    _Pragma("unroll") for (int c = 0; c < 4; c++) {                            \
      float p0 = exp2f(sa[c][0]-MR), p1 = exp2f(sa[c][1]-MR);                  \
      float p2 = exp2f(sa[c][2]-MR), p3 = exp2f(sa[c][3]-MR);                  \
      u64 pk = (u64)cvtpk(p0, p1) | ((u64)cvtpk(p2, p3) << 32);                \
      *(u64*)(pwa[c] + GOFF) = pk;                                             \
    }                                                                          \
    asm volatile("s_waitcnt lgkmcnt(0)" ::: "memory");                         \
    __builtin_amdgcn_sched_barrier(0);                                         \
    const short8 pb0 = *(const short8*)(pra0 + GOFF);                          \
    const short8 pb1 = *(const short8*)(pra1 + GOFF);                          \
    _Pragma("unroll") for (int cd = 0; cd < 4; cd++) {                         \
      O[cd] = __builtin_amdgcn_mfma_f32_16x16x32_bf16(va[cd][0], pb0, O[cd], 0,0,0); \
      O[cd] = __builtin_amdgcn_mfma_f32_16x16x32_bf16(va[cd][1], pb1, O[cd], 0,0,0); \
    }                                                                          \
    ACCL = __builtin_amdgcn_mfma_f32_16x16x32_bf16(ones, pb0, ACCL, 0,0,0);    \
    ACCL = __builtin_amdgcn_mfma_f32_16x16x32_bf16(ones, pb1, ACCL, 0,0,0);    \
  }

#define ATTN_BODY(BOFF) {                                                      \
    short8 ka[4][2], va[4][2];                                                 \
    _Pragma("unroll") for (int c = 0; c < 4; c++)                              \
      _Pragma("unroll") for (int sf = 0; sf < 2; sf++) {                       \
        ka[c][sf] = *(const short8*)(ka_p[c][sf] + (BOFF));                    \
        va[c][sf] = *(const short8*)(va_p[c][sf] + (BOFF));                    \
      }                                                                        \
    GROUP(qf00, qf01, mr0, o0, accl0, 0)                                       \
    GROUP(qf10, qf11, mr1, o1, accl1, 2048)                                    \
  }

__global__ void __launch_bounds__(512, 2) k_attn(
    const ushort_t* __restrict__ Qt, const ushort_t* __restrict__ Kt,
    const ushort_t* __restrict__ Vv,
    const float* __restrict__ oAw, const float* __restrict__ oAb,
    const float* __restrict__ oBw, const float* __restrict__ oBb,
    const ushort_t* __restrict__ xbf, const ushort_t* __restrict__ ybf,
    const float* __restrict__ sums,
    const float* __restrict__ gwA, const float* __restrict__ gbA,
    const float* __restrict__ gwB, const float* __restrict__ gbB,
    float* __restrict__ out) {
  // [0,65536): 2 bufs x 2 slices x {K 8KB, V 8KB}; [65536,98304): plds 4KB/wave;
  // [98304,98816): GN scale/shift. Epilogue: smO[8][16q][64d] at [0,32768), cm/cl at 65536.
  __shared__ __align__(16) char lds[98816];
  const int h = blockIdx.x >> 5;       // 8 heads
  const int qt = blockIdx.x & 31;      // 32 q-tiles of 128
  const int b = h >> 1, br = h & 1;
  const int qh = b * 2 + (1 - br);
  const int tid = threadIdx.x;
  const int lane = tid & 63;
  const int wave = tid >> 6;
  const int s = wave >> 2;             // k-slice (0: keys 0..2047, 1: 2048..4095)
  const int t = wave & 3;              // q-sub-tile of 32
  const int q = lane & 15, g = lane >> 4;

  float* scs = (float*)(lds + 98304);
  float* shs = scs + 64;
  if (tid < 64) {
    float a, sh;
    gn_coeffs(sums, b, br, tid, br ? gwB : gwA, br ? gbB : gbA, a, sh);
    scs[tid] = a;
    shs[tid] = sh;
  }

  // Q fragments: 2 groups of 16q
  const int qb = qt * 128 + t * 32;
  const ushort_t* Qp = Qt + ((qh * HW + qb + q) << 6);
  const short8 qf00 = *(const short8*)(Qp + g * 8);
  const short8 qf01 = *(const short8*)(Qp + 32 + g * 8);
  const short8 qf10 = *(const short8*)(Qp + 1024 + g * 8);      // +16 rows
  const short8 qf11 = *(const short8*)(Qp + 1024 + 32 + g * 8);

  // staging sources (pre-swizzled global addr; LDS dest linear tid*16)
  const ushort_t* Kh = Kt + ((u64)h * HW << 6);
  const ushort_t* Vh = Vv + (u64)h * (CCH * HW);
  const int rr = tid >> 3;                         // 0..63
  const int ck = ((tid & 7) ^ (rr & 7)) << 3;      // swizzled 16B chunk (ushorts)
  const ushort_t* gK0 = Kh + (rr << 6) + ck;               // slice0, +it*4096/tile
  const ushort_t* gK1 = Kh + ((2048 + rr) << 6) + ck;      // slice1
  const ushort_t* gV0 = Vh + rr * HW + ck;                 // slice0, +it*64/tile
  const ushort_t* gV1 = Vh + rr * HW + 2048 + ck;          // slice1

  // fragment read addresses (buf0; buf1 = +32768 immediate)
  const char* kb0 = lds + s * 16384;
  const char* vb0 = kb0 + 8192;
  const char* ka_p[4][2];
  const char* va_p[4][2];
#pragma unroll
  for (int c = 0; c < 4; c++)
#pragma unroll
    for (int sf = 0; sf < 2; sf++) {
      const int o16 = ((c * 16 + q) << 7) + (((sf * 4 + g) ^ (q & 7)) << 4);
      ka_p[c][sf] = kb0 + o16;
      va_p[c][sf] = vb0 + o16;
    }

  // P staging addresses (group1 = +2048 immediate)
  char* wpq = lds + 65536 + wave * 4096 + (q << 7);
  const int sw = (q & 7) << 4;
  char* pwa[4];
#pragma unroll
  for (int c = 0; c < 4; c++) pwa[c] = wpq + (((c << 5) | (g << 3)) ^ sw);
  const char* pra0 = wpq + ((g << 4) ^ sw);
  const char* pra1 = wpq + ((64 | (g << 4)) ^ sw);

  float mr0 = -1e30f, mr1 = -1e30f;
  f32x4 o0[4] = {}, o1[4] = {};
  f32x4 accl0 = {}, accl1 = {};
  short8 ones;
#pragma unroll
  for (int j = 0; j < 8; j++) ones[j] = (short)0x3F80;

  STAGE(0, 0);
#pragma unroll 1
  for (int p2 = 0; p2 < 16; ++p2) {
    STAGE(1, 2 * p2 + 1);
    asm volatile("s_waitcnt vmcnt(4)" ::: "memory");
    __builtin_amdgcn_s_barrier();
    ATTN_BODY(0)
    __builtin_amdgcn_s_barrier();
    if (p2 < 15) {
      STAGE(0, 2 * p2 + 2);
      asm volatile("s_waitcnt vmcnt(4)" ::: "memory");
    } else {
      asm volatile("s_waitcnt vmcnt(0)" ::: "memory");
    }
    __builtin_amdgcn_s_barrier();
    ATTN_BODY(32768)
    __builtin_amdgcn_s_barrier();
  }

  // ---- split-K combine (2 slices) ----
  float* cmA = (float*)(lds + 65536);    // [8 waves][2 grp][16 q]
  float* clA = cmA + 256;
  __syncthreads();
  if (lane < 16) {
    cmA[(wave * 2 + 0) * 16 + q] = mr0;  clA[(wave * 2 + 0) * 16 + q] = accl0[0];
    cmA[(wave * 2 + 1) * 16 + q] = mr1;  clA[(wave * 2 + 1) * 16 + q] = accl1[0];
  }
  for (int i = tid; i < 8192; i += 512) ((float*)lds)[i] = 0.f;   // zero smO
  __syncthreads();
#pragma unroll
  for (int grp = 0; grp < 2; grp++) {
    const float mA = cmA[(t * 2 + grp) * 16 + q];
    const float mB = cmA[((t + 4) * 2 + grp) * 16 + q];
    const float lA = clA[(t * 2 + grp) * 16 + q];
    const float lB = clA[((t + 4) * 2 + grp) * 16 + q];
    const float M = fmaxf(mA, mB);
    const float L = exp2f(mA - M) * lA + exp2f(mB - M) * lB;
    const float scl = exp2f((grp ? mr1 : mr0) - M) / L;
    float* smW = (float*)(lds + (t * 2 + grp) * 4096);
#pragma unroll
    for (int cd = 0; cd < 4; cd++)
#pragma unroll
      for (int i = 0; i < 4; i++) {
        const float v = (grp ? o1[cd][i] : o0[cd][i]) * scl;
        atomicAdd(&smW[q * 64 + (((cd * 4 + g) ^ q) << 2) + i], v);
      }
  }
  __syncthreads();

  // ---- fused epilogue: out-proj + bias + residual; wave w owns 16q sub-tile w ----
  const float* W    = br ? oBw : oAw;
  const float* bias = br ? oBb : oAb;
  const ushort_t* xR = (br ? ybf : xbf) + b * (CCH * HW);
  const int q2 = lane & 15, g2 = lane >> 4;
  const float* smR = (float*)(lds + wave * 4096) + q2 * 64;
  const int pix = qt * 128 + wave * 16 + q2;

  float acc[16];
#pragma unroll
  for (int oi = 0; oi < 16; oi++) acc[oi] = bias[g2 * 16 + oi];
#pragma unroll
  for (int c4 = 0; c4 < 16; c4++) {
    const f32x4 Lv = *(const f32x4*)(smR + ((c4 ^ q2) << 2));
#pragma unroll
    for (int oi = 0; oi < 16; oi++) {
      const f32x4 wv = *(const f32x4*)(W + (g2 * 16 + oi) * 64 + c4 * 4);
      acc[oi] += wv[0] * Lv[0] + wv[1] * Lv[1] + wv[2] * Lv[2] + wv[3] * Lv[3];
    }
  }
#pragma unroll
  for (int oi = 0; oi < 16; oi++) {
    const int ch = g2 * 16 + oi;
    const float xn = b2f(xR[ch * HW + pix]) * scs[ch] + shs[ch];
    out[(b * 128 + br * 64 + ch) * HW + pix] = acc[oi] + xn;
  }
}

extern "C" void kernel_launch(void* const* d_in, const int* in_sizes, int n_in,
                              void* d_out, int out_size, void* d_ws, size_t ws_size,
                              hipStream_t stream) {
  const float* in   = (const float*)d_in[0];
  const float* dw1w = (const float*)d_in[1];
  const float* dw1b = (const float*)d_in[2];
  const float* dw2w = (const float*)d_in[3];
  const float* dw2b = (const float*)d_in[4];
  const float* gnAw = (const float*)d_in[5];
  const float* gnAb = (const float*)d_in[6];
  const float* gnBw = (const float*)d_in[7];
  const float* gnBb = (const float*)d_in[8];
  const float* qAw  = (const float*)d_in[9];
  const float* qBw  = (const float*)d_in[10];
  const float* oAw  = (const float*)d_in[11];
  const float* oAb  = (const float*)d_in[12];
  const float* oBw  = (const float*)d_in[13];
  const float* oBb  = (const float*)d_in[14];
  float* out = (float*)d_out;

  // workspace: 16 MB + 16 KB
  char* ws = (char*)d_ws;
  ushort_t* xbf = (ushort_t*)ws;             // [4][64][4096] bf16 conv out A
  ushort_t* ybf = xbf + 1048576;             // [4][64][4096] bf16 conv out B
  ushort_t* Qt  = ybf + 1048576;             // [8][4096][64] bf16 (pre-scaled)
  ushort_t* Kt  = Qt + 2097152;              // [8][4096][64] bf16
  ushort_t* Vv  = Kt + 2097152;              // [8][64][4096] bf16
  float* sums   = (float*)(Vv + 2097152);    // [2][256 bc][4 strip][2] f32 partials

  k_dwconv<<<1024, 256, 0, stream>>>(in, dw1w, dw1b, dw2w, dw2b, xbf, ybf, sums);
  k_qkv<<<768, 256, 0, stream>>>(xbf, ybf, sums, gnAw, gnAb, gnBw, gnBb,
                                 qAw, qBw, Qt, Kt, Vv);
  k_attn<<<256, 512, 0, stream>>>(Qt, Kt, Vv, oAw, oAb, oBw, oBb,
                                  xbf, ybf, sums, gnAw, gnAb, gnBw, gnBb, out);
}